// Round 5
// baseline (276.247 us; speedup 1.0000x reference)
//
#include <hip/hip_runtime.h>

#define B_N 8192
#define D_N 1024
#define C_N 1024
#define GRID 512
#define BM 128
#define BN 128
#define BK 64

typedef __attribute__((ext_vector_type(8))) __bf16 bf16x8;
typedef __attribute__((ext_vector_type(4))) float floatx4;

__device__ inline unsigned short f2bf(float f) {
  union { float f; unsigned int u; } cv; cv.f = f;
  unsigned int b = cv.u;
  unsigned int r = (b + 0x7FFFu + ((b >> 16) & 1u)) >> 16;  // RNE
  return (unsigned short)r;
}
__device__ inline float d4(const float4 a) {
  return a.x * a.x + a.y * a.y + a.z * a.z + a.w * a.w;
}
__device__ inline ushort4 pk4(const float4 v, const float s) {
  ushort4 u;
  u.x = f2bf(v.x * s); u.y = f2bf(v.y * s);
  u.z = f2bf(v.z * s); u.w = f2bf(v.w * s);
  return u;
}

// Device-scope grid barrier (proven correct in R4). All GRID=512 blocks
// co-resident: launch_bounds(256,2) -> <=256 regs/thread -> 2 blocks/CU,
// LDS 33KB*2 <= 160KB. Counter padded to its own cache line by caller.
__device__ inline void grid_barrier(int* counter) {
  __syncthreads();
  if (threadIdx.x == 0) {
    __threadfence();
    __hip_atomic_fetch_add(counter, 1, __ATOMIC_RELEASE, __HIP_MEMORY_SCOPE_AGENT);
    while (__hip_atomic_load(counter, __ATOMIC_ACQUIRE, __HIP_MEMORY_SCOPE_AGENT) < GRID)
      __builtin_amdgcn_s_sleep(1);
    __threadfence();
  }
  __syncthreads();
}

__global__ __launch_bounds__(256, 2) void fused_kernel(
    const float* __restrict__ emb_i, const float* __restrict__ emb_j,
    const int* __restrict__ labels,
    unsigned short* __restrict__ z_j, unsigned short* __restrict__ proto,
    float* __restrict__ p2, int* __restrict__ cnt, int* __restrict__ idx,
    int* __restrict__ bar, float* __restrict__ out) {
  __shared__ __align__(16) unsigned short As[BM * BK];
  __shared__ __align__(16) unsigned short Bs[BN * BK];
  __shared__ float sx[4][8];
  __shared__ float sred[4];

  const int t = threadIdx.x;
  const int lane = t & 63;
  const int wid = t >> 6;
  const int blk = blockIdx.x;

  // ---------------- Phase A: normalize emb_j -> z_j bf16; build idx --------
  if (t < 16) {
    const int row = blk * 16 + t;
    const int lab = labels[row];
    const int pos = atomicAdd(&cnt[lab], 1) & 7;  // exactly 8 per class
    idx[lab * 8 + pos] = row;
  }
#pragma unroll
  for (int r = 0; r < 4; ++r) {
    const int row = blk * 16 + wid * 4 + r;
    const float4* src = (const float4*)(emb_j + (size_t)row * D_N);
    const float4 v0 = src[lane], v1 = src[lane + 64];
    const float4 v2 = src[lane + 128], v3 = src[lane + 192];
    float ss = d4(v0) + d4(v1) + d4(v2) + d4(v3);
    for (int o = 32; o; o >>= 1) ss += __shfl_xor(ss, o, 64);
    const float inv = 1.0f / fmaxf(sqrtf(ss), 1e-12f);
    ushort4* dst = (ushort4*)(z_j + (size_t)row * D_N);
    dst[lane] = pk4(v0, inv);
    dst[lane + 64] = pk4(v1, inv);
    dst[lane + 128] = pk4(v2, inv);
    dst[lane + 192] = pk4(v3, inv);
  }

  grid_barrier(&bar[0]);

  // ---------------- Phase B: prototypes from raw emb_i ---------------------
  // 2 classes/block processed sequentially; all 4 waves on one class, each
  // wave owns a quarter of D (256 floats = 1 float4/lane/row) -> only 32
  // VGPRs of row data live (spill-proof).
#pragma unroll 1
  for (int cc = 0; cc < 2; ++cc) {
    const int c = blk * 2 + cc;
    const float* base = emb_i + wid * 256;
    float4 v[8];
    float ss[8];
#pragma unroll
    for (int k = 0; k < 8; ++k) {
      const int row = idx[c * 8 + k];
      v[k] = ((const float4*)(base + (size_t)row * D_N))[lane];
      ss[k] = d4(v[k]);
    }
#pragma unroll
    for (int k = 0; k < 8; ++k)
      for (int o = 32; o; o >>= 1) ss[k] += __shfl_xor(ss[k], o, 64);
    if (lane == 0) {
#pragma unroll
      for (int k = 0; k < 8; ++k) sx[wid][k] = ss[k];
    }
    __syncthreads();
    float4 a = make_float4(0.f, 0.f, 0.f, 0.f);
#pragma unroll
    for (int k = 0; k < 8; ++k) {
      const float tot = sx[0][k] + sx[1][k] + sx[2][k] + sx[3][k];
      const float iv = 1.0f / fmaxf(sqrtf(tot), 1e-12f);
      a.x += v[k].x * iv; a.y += v[k].y * iv;
      a.z += v[k].z * iv; a.w += v[k].w * iv;
    }
    a.x *= 0.125f; a.y *= 0.125f; a.z *= 0.125f; a.w *= 0.125f;

    float pp = d4(a);
    for (int o = 32; o; o >>= 1) pp += __shfl_xor(pp, o, 64);
    __syncthreads();  // all sx readers done before reuse
    if (lane == 0) sx[wid][0] = pp;
    __syncthreads();
    if (t == 0) p2[c] = sx[0][0] + sx[1][0] + sx[2][0] + sx[3][0];

    ((ushort4*)(proto + (size_t)c * D_N + wid * 256))[lane] = pk4(a, 1.0f);
  }

  grid_barrier(&bar[32]);

  // ---------------- Phase C: bf16 GEMM (z_j @ proto^T) + BCE epilogue ------
  const int bm = blk & 63;
  const int bn = blk >> 6;

  floatx4 acc[4][4];
#pragma unroll
  for (int i = 0; i < 4; ++i)
#pragma unroll
    for (int j = 0; j < 4; ++j)
      acc[i][j] = (floatx4){0.f, 0.f, 0.f, 0.f};

  const int wm = (wid >> 1) * 64;
  const int wn = (wid & 1) * 64;
  // XOR-swizzled staging (verified conflict-free in R2): LDS chunk slot
  // cs=t%8 holds global chunk cs^(row&7); inverse applied on ds_read side.
  const int srow = t >> 3;
  const int scol = (((t & 7) ^ (srow & 7)) << 3);
  const unsigned short* Ag = z_j + (size_t)(bm * BM + srow) * D_N + scol;
  const unsigned short* Bg = proto + (size_t)(bn * BN + srow) * D_N + scol;
  unsigned short* Al = As + t * 8;
  unsigned short* Bl = Bs + t * 8;

  for (int k0 = 0; k0 < D_N; k0 += BK) {
#pragma unroll
    for (int it = 0; it < 4; ++it) {
      __builtin_amdgcn_global_load_lds(
          (const __attribute__((address_space(1))) void*)(Ag + (size_t)it * 32 * D_N + k0),
          (__attribute__((address_space(3))) void*)(Al + it * 2048), 16, 0, 0);
      __builtin_amdgcn_global_load_lds(
          (const __attribute__((address_space(1))) void*)(Bg + (size_t)it * 32 * D_N + k0),
          (__attribute__((address_space(3))) void*)(Bl + it * 2048), 16, 0, 0);
    }
    __syncthreads();
#pragma unroll
    for (int kk = 0; kk < BK; kk += 32) {
      const int swz = ((((kk >> 3) + (lane >> 4)) ^ (lane & 7)) << 3);
      bf16x8 af[4], bfr[4];
#pragma unroll
      for (int mi = 0; mi < 4; ++mi)
        af[mi] = *(const bf16x8*)(As + (wm + mi * 16 + (lane & 15)) * BK + swz);
#pragma unroll
      for (int ni = 0; ni < 4; ++ni)
        bfr[ni] = *(const bf16x8*)(Bs + (wn + ni * 16 + (lane & 15)) * BK + swz);
#pragma unroll
      for (int mi = 0; mi < 4; ++mi)
#pragma unroll
        for (int ni = 0; ni < 4; ++ni)
          acc[mi][ni] = __builtin_amdgcn_mfma_f32_16x16x32_bf16(af[mi], bfr[ni], acc[mi][ni], 0, 0, 0);
    }
    __syncthreads();
  }

  // epilogue: C/D layout col=lane&15, row=(lane>>4)*4+reg
  const int colb = bn * BN + wn + (lane & 15);
  const int rowb = bm * BM + wm + ((lane >> 4) << 2);
  float p2c[4];
#pragma unroll
  for (int ni = 0; ni < 4; ++ni) p2c[ni] = p2[colb + ni * 16];

  float lsum = 0.f;
#pragma unroll
  for (int mi = 0; mi < 4; ++mi) {
#pragma unroll
    for (int r = 0; r < 4; ++r) {
      const int row = rowb + mi * 16 + r;
      const int lab = labels[row];
#pragma unroll
      for (int ni = 0; ni < 4; ++ni) {
        const float dot = acc[mi][ni][r];
        const float d2 = 1.0f + p2c[ni] - 2.0f * dot;
        const float s = 2.0f - sqrtf(fmaxf(d2, 0.0f));
        const float sp = fmaxf(s, 0.0f) + log1pf(expf(-fabsf(s)));
        lsum += sp - ((lab == colb + ni * 16) ? s : 0.0f);
      }
    }
  }
  for (int o = 32; o; o >>= 1) lsum += __shfl_xor(lsum, o, 64);
  if (lane == 0) sred[wid] = lsum;
  __syncthreads();
  if (t == 0)
    atomicAdd(out, (sred[0] + sred[1] + sred[2] + sred[3]) *
                       (1.0f / ((float)B_N * (float)C_N)));
}

// ---------------------------------------------------------------------------
extern "C" void kernel_launch(void* const* d_in, const int* in_sizes, int n_in,
                              void* d_out, int out_size, void* d_ws, size_t ws_size,
                              hipStream_t stream) {
  const float* emb_i = (const float*)d_in[0];
  const float* emb_j = (const float*)d_in[1];
  const int* labels = (const int*)d_in[2];
  float* out = (float*)d_out;

  char* ws = (char*)d_ws;
  unsigned short* z_j = (unsigned short*)ws;                         // 16 MB
  unsigned short* proto = (unsigned short*)(ws + (size_t)16777216);  // 2 MB
  float* p2 = (float*)(ws + (size_t)18874368);                       // 4 KB
  int* cnt = (int*)(ws + (size_t)18878464);                          // 4 KB
  int* idx = (int*)(ws + (size_t)18882560);                          // 32 KB
  int* bar = (int*)(ws + (size_t)18915328);                          // 2 cache lines

  hipMemsetAsync(cnt, 0, C_N * sizeof(int), stream);
  hipMemsetAsync(bar, 0, 33 * sizeof(int), stream);
  hipMemsetAsync(out, 0, sizeof(float), stream);
  fused_kernel<<<dim3(GRID), 256, 0, stream>>>(emb_i, emb_j, labels, z_j,
                                               proto, p2, cnt, idx, bar, out);
}

// Round 6
// 154.645 us; speedup vs baseline: 1.7863x; 1.7863x over previous
//
#include <hip/hip_runtime.h>

#define B_N 8192
#define D_N 1024
#define C_N 1024
#define BM 128
#define BN 128
#define BK 64

typedef __attribute__((ext_vector_type(8))) __bf16 bf16x8;
typedef __attribute__((ext_vector_type(4))) float floatx4;

__device__ inline unsigned short f2bf(float f) {
  union { float f; unsigned int u; } cv; cv.f = f;
  unsigned int b = cv.u;
  unsigned int r = (b + 0x7FFFu + ((b >> 16) & 1u)) >> 16;  // RNE
  return (unsigned short)r;
}
__device__ inline float d4(const float4 a) {
  return a.x * a.x + a.y * a.y + a.z * a.z + a.w * a.w;
}
__device__ inline ushort4 pk4(const float4 v, const float s) {
  ushort4 u;
  u.x = f2bf(v.x * s); u.y = f2bf(v.y * s);
  u.z = f2bf(v.z * s); u.w = f2bf(v.w * s);
  return u;
}

// ---------------------------------------------------------------------------
// prep_kernel: ONE dispatch, two independent jobs (no cross-block deps):
//   blocks [0, B_N):      normalize emb_j row -> z_j (bf16)
//   blocks [B_N, B_N+C_N): class c = blk-B_N: scan labels (32KB, L2-resident)
//                          for its 8 member rows, normalize raw emb_i rows
//                          in-register, mean -> proto (bf16) + p2.
// Block B_N also zeroes out[0] (replaces a memset dispatch; gemm's atomicAdds
// are stream-ordered after this kernel completes).
// ---------------------------------------------------------------------------
__global__ __launch_bounds__(256) void prep_kernel(
    const float* __restrict__ emb_i, const float* __restrict__ emb_j,
    const int* __restrict__ labels,
    unsigned short* __restrict__ z_j, unsigned short* __restrict__ proto,
    float* __restrict__ p2, float* __restrict__ out) {
  __shared__ float sred[4];
  __shared__ float sx[4][8];
  __shared__ int list[8];
  __shared__ int scnt;

  const int t = threadIdx.x;
  const int lane = t & 63;
  const int wid = t >> 6;

  if (blockIdx.x < B_N) {
    // ---- normalize one emb_j row -> bf16 ----
    const int row = blockIdx.x;
    const float4 v = ((const float4*)(emb_j + (size_t)row * D_N))[t];
    float ss = d4(v);
    for (int o = 32; o; o >>= 1) ss += __shfl_xor(ss, o, 64);
    if (lane == 0) sred[wid] = ss;
    __syncthreads();
    const float tot = sred[0] + sred[1] + sred[2] + sred[3];
    const float inv = 1.0f / fmaxf(sqrtf(tot), 1e-12f);
    ((ushort4*)(z_j + (size_t)row * D_N))[t] = pk4(v, inv);
    return;
  }

  // ---- prototype for class c ----
  const int c = blockIdx.x - B_N;
  if (c == 0 && t == 0) out[0] = 0.0f;  // replaces memset dispatch

  if (t == 0) scnt = 0;
  __syncthreads();
  for (int base = 0; base < B_N; base += 256) {
    if (labels[base + t] == c) {
      const int p = atomicAdd(&scnt, 1) & 7;  // exactly 8 per class
      list[p] = base + t;
    }
  }
  __syncthreads();

  // 4 waves, each owns a quarter of D (256 floats = 1 float4/lane/row)
  const float* base = emb_i + wid * 256;
  float4 v[8];
  float ss[8];
#pragma unroll
  for (int k = 0; k < 8; ++k) {
    v[k] = ((const float4*)(base + (size_t)list[k] * D_N))[lane];
    ss[k] = d4(v[k]);
  }
#pragma unroll
  for (int k = 0; k < 8; ++k)
    for (int o = 32; o; o >>= 1) ss[k] += __shfl_xor(ss[k], o, 64);
  if (lane == 0) {
#pragma unroll
    for (int k = 0; k < 8; ++k) sx[wid][k] = ss[k];
  }
  __syncthreads();

  float4 a = make_float4(0.f, 0.f, 0.f, 0.f);
#pragma unroll
  for (int k = 0; k < 8; ++k) {
    const float tot = sx[0][k] + sx[1][k] + sx[2][k] + sx[3][k];
    const float iv = 1.0f / fmaxf(sqrtf(tot), 1e-12f);
    a.x += v[k].x * iv; a.y += v[k].y * iv;
    a.z += v[k].z * iv; a.w += v[k].w * iv;
  }
  a.x *= 0.125f; a.y *= 0.125f; a.z *= 0.125f; a.w *= 0.125f;

  float pp = d4(a);
  for (int o = 32; o; o >>= 1) pp += __shfl_xor(pp, o, 64);
  __syncthreads();  // all sx readers done before reuse
  if (lane == 0) sx[wid][0] = pp;
  __syncthreads();
  if (t == 0) p2[c] = sx[0][0] + sx[1][0] + sx[2][0] + sx[3][0];

  ((ushort4*)(proto + (size_t)c * D_N + wid * 256))[lane] = pk4(a, 1.0f);
}

// ---------------------------------------------------------------------------
// gemm_loss_kernel: proven R2/R3 structure. bf16 GEMM (z_j @ proto^T),
// 128x128 tile, BK=64, global_load_lds width=16, XOR-swizzled LDS
// (conflict-free), 2x2 waves of 64x64, 16x16x32 bf16 MFMA, fused BCE
// epilogue, one fp32 atomicAdd per block (out zeroed by prep).
// ---------------------------------------------------------------------------
__global__ __launch_bounds__(256) void gemm_loss_kernel(
    const unsigned short* __restrict__ Zj,   // [B,D] bf16
    const unsigned short* __restrict__ P,    // [C,D] bf16
    const float* __restrict__ p2,            // [C]
    const int* __restrict__ labels,          // [B]
    float* __restrict__ out) {               // scalar (zeroed by prep)
  __shared__ __align__(16) unsigned short As[BM * BK];
  __shared__ __align__(16) unsigned short Bs[BN * BK];
  __shared__ float sred[4];

  const int t = threadIdx.x;
  const int lane = t & 63;
  const int wid = t >> 6;
  const int wm = (wid >> 1) * 64;
  const int wn = (wid & 1) * 64;
  const int bm = blockIdx.x;
  const int bn = blockIdx.y;

  floatx4 acc[4][4];
#pragma unroll
  for (int i = 0; i < 4; ++i)
#pragma unroll
    for (int j = 0; j < 4; ++j)
      acc[i][j] = (floatx4){0.f, 0.f, 0.f, 0.f};

  const int srow = t >> 3;
  const int scol = (((t & 7) ^ (srow & 7)) << 3);
  const unsigned short* Ag = Zj + (size_t)(bm * BM + srow) * D_N + scol;
  const unsigned short* Bg = P + (size_t)(bn * BN + srow) * D_N + scol;
  unsigned short* Al = As + t * 8;
  unsigned short* Bl = Bs + t * 8;

  for (int k0 = 0; k0 < D_N; k0 += BK) {
#pragma unroll
    for (int it = 0; it < 4; ++it) {
      __builtin_amdgcn_global_load_lds(
          (const __attribute__((address_space(1))) void*)(Ag + (size_t)it * 32 * D_N + k0),
          (__attribute__((address_space(3))) void*)(Al + it * 2048), 16, 0, 0);
      __builtin_amdgcn_global_load_lds(
          (const __attribute__((address_space(1))) void*)(Bg + (size_t)it * 32 * D_N + k0),
          (__attribute__((address_space(3))) void*)(Bl + it * 2048), 16, 0, 0);
    }
    __syncthreads();
#pragma unroll
    for (int kk = 0; kk < BK; kk += 32) {
      const int swz = ((((kk >> 3) + (lane >> 4)) ^ (lane & 7)) << 3);
      bf16x8 af[4], bfr[4];
#pragma unroll
      for (int mi = 0; mi < 4; ++mi)
        af[mi] = *(const bf16x8*)(As + (wm + mi * 16 + (lane & 15)) * BK + swz);
#pragma unroll
      for (int ni = 0; ni < 4; ++ni)
        bfr[ni] = *(const bf16x8*)(Bs + (wn + ni * 16 + (lane & 15)) * BK + swz);
#pragma unroll
      for (int mi = 0; mi < 4; ++mi)
#pragma unroll
        for (int ni = 0; ni < 4; ++ni)
          acc[mi][ni] = __builtin_amdgcn_mfma_f32_16x16x32_bf16(af[mi], bfr[ni], acc[mi][ni], 0, 0, 0);
    }
    __syncthreads();
  }

  // epilogue: C/D layout col=lane&15, row=(lane>>4)*4+reg
  const int colb = bn * BN + wn + (lane & 15);
  const int rowb = bm * BM + wm + ((lane >> 4) << 2);
  float p2c[4];
#pragma unroll
  for (int ni = 0; ni < 4; ++ni) p2c[ni] = p2[colb + ni * 16];

  float lsum = 0.f;
#pragma unroll
  for (int mi = 0; mi < 4; ++mi) {
#pragma unroll
    for (int r = 0; r < 4; ++r) {
      const int row = rowb + mi * 16 + r;
      const int lab = labels[row];
#pragma unroll
      for (int ni = 0; ni < 4; ++ni) {
        const float dot = acc[mi][ni][r];
        const float d2 = 1.0f + p2c[ni] - 2.0f * dot;
        const float s = 2.0f - sqrtf(fmaxf(d2, 0.0f));
        const float sp = fmaxf(s, 0.0f) + log1pf(expf(-fabsf(s)));
        lsum += sp - ((lab == colb + ni * 16) ? s : 0.0f);
      }
    }
  }
  for (int o = 32; o; o >>= 1) lsum += __shfl_xor(lsum, o, 64);
  if (lane == 0) sred[wid] = lsum;
  __syncthreads();
  if (t == 0)
    atomicAdd(out, (sred[0] + sred[1] + sred[2] + sred[3]) *
                       (1.0f / ((float)B_N * (float)C_N)));
}

// ---------------------------------------------------------------------------
extern "C" void kernel_launch(void* const* d_in, const int* in_sizes, int n_in,
                              void* d_out, int out_size, void* d_ws, size_t ws_size,
                              hipStream_t stream) {
  const float* emb_i = (const float*)d_in[0];
  const float* emb_j = (const float*)d_in[1];
  const int* labels = (const int*)d_in[2];
  float* out = (float*)d_out;

  char* ws = (char*)d_ws;
  unsigned short* z_j = (unsigned short*)ws;                         // 16 MB
  unsigned short* proto = (unsigned short*)(ws + (size_t)16777216);  // 2 MB
  float* p2 = (float*)(ws + (size_t)18874368);                       // 4 KB

  prep_kernel<<<dim3(B_N + C_N), 256, 0, stream>>>(emb_i, emb_j, labels, z_j,
                                                   proto, p2, out);
  gemm_loss_kernel<<<dim3(B_N / BM, C_N / BN), 256, 0, stream>>>(z_j, proto,
                                                                 p2, labels, out);
}

// Round 7
// 147.414 us; speedup vs baseline: 1.8740x; 1.0491x over previous
//
#include <hip/hip_runtime.h>

#define B_N 8192
#define D_N 1024
#define C_N 1024
#define BM 128
#define BN 128
#define BK 64

typedef __attribute__((ext_vector_type(8))) __bf16 bf16x8;
typedef __attribute__((ext_vector_type(4))) float floatx4;

__device__ inline unsigned short f2bf(float f) {
  union { float f; unsigned int u; } cv; cv.f = f;
  unsigned int b = cv.u;
  unsigned int r = (b + 0x7FFFu + ((b >> 16) & 1u)) >> 16;  // RNE
  return (unsigned short)r;
}
__device__ inline float d4(const float4 a) {
  return a.x * a.x + a.y * a.y + a.z * a.z + a.w * a.w;
}
__device__ inline ushort4 pk4(const float4 v, const float s) {
  ushort4 u;
  u.x = f2bf(v.x * s); u.y = f2bf(v.y * s);
  u.z = f2bf(v.z * s); u.w = f2bf(v.w * s);
  return u;
}

// ---------------------------------------------------------------------------
// prep_kernel: 1024 FAT blocks (WG-dispatch-rate theory: 9216 tiny WGs were
// launch-bound at ~10ns/WG). Each block:
//   part 1: normalize 8 emb_j rows -> z_j bf16 (one row per wave per iter,
//           in-wave shuffle reduce only — no LDS, no syncthreads)
//   part 2: prototype for class c = blockIdx.x: int4-scan labels (8 iters),
//           gather 8 raw emb_i rows, normalize in-register, mean -> proto+p2.
// Block 0 thread 0 zeroes out[0] (gemm atomicAdds are stream-ordered after).
// ---------------------------------------------------------------------------
__global__ __launch_bounds__(256) void prep_kernel(
    const float* __restrict__ emb_i, const float* __restrict__ emb_j,
    const int* __restrict__ labels,
    unsigned short* __restrict__ z_j, unsigned short* __restrict__ proto,
    float* __restrict__ p2, float* __restrict__ out) {
  __shared__ float sx[4][8];
  __shared__ int list[8];
  __shared__ int scnt;

  const int t = threadIdx.x;
  const int lane = t & 63;
  const int wid = t >> 6;
  const int blk = blockIdx.x;

  if (t == 0) scnt = 0;
  if (blk == 0 && t == 0) out[0] = 0.0f;

  // ---- part 1: 8 rows of emb_j, one per wave per iteration ----
#pragma unroll
  for (int it = 0; it < 2; ++it) {
    const int row = blk * 8 + it * 4 + wid;
    const float4* src = (const float4*)(emb_j + (size_t)row * D_N);
    const float4 v0 = src[lane], v1 = src[lane + 64];
    const float4 v2 = src[lane + 128], v3 = src[lane + 192];
    float ss = d4(v0) + d4(v1) + d4(v2) + d4(v3);
    for (int o = 32; o; o >>= 1) ss += __shfl_xor(ss, o, 64);
    const float inv = 1.0f / fmaxf(sqrtf(ss), 1e-12f);
    ushort4* dst = (ushort4*)(z_j + (size_t)row * D_N);
    dst[lane] = pk4(v0, inv);
    dst[lane + 64] = pk4(v1, inv);
    dst[lane + 128] = pk4(v2, inv);
    dst[lane + 192] = pk4(v3, inv);
  }

  // ---- part 2: prototype for class c = blk ----
  const int c = blk;
  __syncthreads();  // scnt=0 visible
  const int4* lab4 = (const int4*)labels;
  for (int i = 0; i < 8; ++i) {
    const int q = i * 256 + t;
    const int4 L = lab4[q];
    const int base = q * 4;
    if (L.x == c) list[atomicAdd(&scnt, 1) & 7] = base;
    if (L.y == c) list[atomicAdd(&scnt, 1) & 7] = base + 1;
    if (L.z == c) list[atomicAdd(&scnt, 1) & 7] = base + 2;
    if (L.w == c) list[atomicAdd(&scnt, 1) & 7] = base + 3;
  }
  __syncthreads();

  // 4 waves, each owns a quarter of D (1 float4/lane/row -> 32 VGPRs live)
  const float* base = emb_i + wid * 256;
  float4 v[8];
  float ss[8];
#pragma unroll
  for (int k = 0; k < 8; ++k) {
    v[k] = ((const float4*)(base + (size_t)list[k] * D_N))[lane];
    ss[k] = d4(v[k]);
  }
#pragma unroll
  for (int k = 0; k < 8; ++k)
    for (int o = 32; o; o >>= 1) ss[k] += __shfl_xor(ss[k], o, 64);
  if (lane == 0) {
#pragma unroll
    for (int k = 0; k < 8; ++k) sx[wid][k] = ss[k];
  }
  __syncthreads();

  float4 a = make_float4(0.f, 0.f, 0.f, 0.f);
#pragma unroll
  for (int k = 0; k < 8; ++k) {
    const float tot = sx[0][k] + sx[1][k] + sx[2][k] + sx[3][k];
    const float iv = 1.0f / fmaxf(sqrtf(tot), 1e-12f);
    a.x += v[k].x * iv; a.y += v[k].y * iv;
    a.z += v[k].z * iv; a.w += v[k].w * iv;
  }
  a.x *= 0.125f; a.y *= 0.125f; a.z *= 0.125f; a.w *= 0.125f;

  float pp = d4(a);
  for (int o = 32; o; o >>= 1) pp += __shfl_xor(pp, o, 64);
  __syncthreads();  // all sx readers done before reuse
  if (lane == 0) sx[wid][0] = pp;
  __syncthreads();
  if (t == 0) p2[c] = sx[0][0] + sx[1][0] + sx[2][0] + sx[3][0];

  ((ushort4*)(proto + (size_t)c * D_N + wid * 256))[lane] = pk4(a, 1.0f);
}

// ---------------------------------------------------------------------------
// gemm_loss_kernel: proven R2/R3/R6 structure (unchanged). bf16 GEMM
// (z_j @ proto^T), 128x128 tile, BK=64, global_load_lds width=16,
// XOR-swizzled LDS (conflict-free), 2x2 waves of 64x64, 16x16x32 bf16 MFMA,
// fused BCE epilogue, one fp32 atomicAdd per block.
// ---------------------------------------------------------------------------
__global__ __launch_bounds__(256) void gemm_loss_kernel(
    const unsigned short* __restrict__ Zj,   // [B,D] bf16
    const unsigned short* __restrict__ P,    // [C,D] bf16
    const float* __restrict__ p2,            // [C]
    const int* __restrict__ labels,          // [B]
    float* __restrict__ out) {               // scalar (zeroed by prep)
  __shared__ __align__(16) unsigned short As[BM * BK];
  __shared__ __align__(16) unsigned short Bs[BN * BK];
  __shared__ float sred[4];

  const int t = threadIdx.x;
  const int lane = t & 63;
  const int wid = t >> 6;
  const int wm = (wid >> 1) * 64;
  const int wn = (wid & 1) * 64;
  const int bm = blockIdx.x;
  const int bn = blockIdx.y;

  floatx4 acc[4][4];
#pragma unroll
  for (int i = 0; i < 4; ++i)
#pragma unroll
    for (int j = 0; j < 4; ++j)
      acc[i][j] = (floatx4){0.f, 0.f, 0.f, 0.f};

  const int srow = t >> 3;
  const int scol = (((t & 7) ^ (srow & 7)) << 3);
  const unsigned short* Ag = Zj + (size_t)(bm * BM + srow) * D_N + scol;
  const unsigned short* Bg = P + (size_t)(bn * BN + srow) * D_N + scol;
  unsigned short* Al = As + t * 8;
  unsigned short* Bl = Bs + t * 8;

  for (int k0 = 0; k0 < D_N; k0 += BK) {
#pragma unroll
    for (int it = 0; it < 4; ++it) {
      __builtin_amdgcn_global_load_lds(
          (const __attribute__((address_space(1))) void*)(Ag + (size_t)it * 32 * D_N + k0),
          (__attribute__((address_space(3))) void*)(Al + it * 2048), 16, 0, 0);
      __builtin_amdgcn_global_load_lds(
          (const __attribute__((address_space(1))) void*)(Bg + (size_t)it * 32 * D_N + k0),
          (__attribute__((address_space(3))) void*)(Bl + it * 2048), 16, 0, 0);
    }
    __syncthreads();
#pragma unroll
    for (int kk = 0; kk < BK; kk += 32) {
      const int swz = ((((kk >> 3) + (lane >> 4)) ^ (lane & 7)) << 3);
      bf16x8 af[4], bfr[4];
#pragma unroll
      for (int mi = 0; mi < 4; ++mi)
        af[mi] = *(const bf16x8*)(As + (wm + mi * 16 + (lane & 15)) * BK + swz);
#pragma unroll
      for (int ni = 0; ni < 4; ++ni)
        bfr[ni] = *(const bf16x8*)(Bs + (wn + ni * 16 + (lane & 15)) * BK + swz);
#pragma unroll
      for (int mi = 0; mi < 4; ++mi)
#pragma unroll
        for (int ni = 0; ni < 4; ++ni)
          acc[mi][ni] = __builtin_amdgcn_mfma_f32_16x16x32_bf16(af[mi], bfr[ni], acc[mi][ni], 0, 0, 0);
    }
    __syncthreads();
  }

  // epilogue: C/D layout col=lane&15, row=(lane>>4)*4+reg
  const int colb = bn * BN + wn + (lane & 15);
  const int rowb = bm * BM + wm + ((lane >> 4) << 2);
  float p2c[4];
#pragma unroll
  for (int ni = 0; ni < 4; ++ni) p2c[ni] = p2[colb + ni * 16];

  float lsum = 0.f;
#pragma unroll
  for (int mi = 0; mi < 4; ++mi) {
#pragma unroll
    for (int r = 0; r < 4; ++r) {
      const int row = rowb + mi * 16 + r;
      const int lab = labels[row];
#pragma unroll
      for (int ni = 0; ni < 4; ++ni) {
        const float dot = acc[mi][ni][r];
        const float d2 = 1.0f + p2c[ni] - 2.0f * dot;
        const float s = 2.0f - sqrtf(fmaxf(d2, 0.0f));
        const float sp = fmaxf(s, 0.0f) + log1pf(expf(-fabsf(s)));
        lsum += sp - ((lab == colb + ni * 16) ? s : 0.0f);
      }
    }
  }
  for (int o = 32; o; o >>= 1) lsum += __shfl_xor(lsum, o, 64);
  if (lane == 0) sred[wid] = lsum;
  __syncthreads();
  if (t == 0)
    atomicAdd(out, (sred[0] + sred[1] + sred[2] + sred[3]) *
                       (1.0f / ((float)B_N * (float)C_N)));
}

// ---------------------------------------------------------------------------
extern "C" void kernel_launch(void* const* d_in, const int* in_sizes, int n_in,
                              void* d_out, int out_size, void* d_ws, size_t ws_size,
                              hipStream_t stream) {
  const float* emb_i = (const float*)d_in[0];
  const float* emb_j = (const float*)d_in[1];
  const int* labels = (const int*)d_in[2];
  float* out = (float*)d_out;

  char* ws = (char*)d_ws;
  unsigned short* z_j = (unsigned short*)ws;                         // 16 MB
  unsigned short* proto = (unsigned short*)(ws + (size_t)16777216);  // 2 MB
  float* p2 = (float*)(ws + (size_t)18874368);                       // 4 KB

  prep_kernel<<<dim3(C_N), 256, 0, stream>>>(emb_i, emb_j, labels, z_j,
                                             proto, p2, out);
  gemm_loss_kernel<<<dim3(B_N / BM, C_N / BN), 256, 0, stream>>>(z_j, proto,
                                                                 p2, labels, out);
}

// Round 8
// 145.981 us; speedup vs baseline: 1.8923x; 1.0098x over previous
//
#include <hip/hip_runtime.h>

#define B_N 8192
#define D_N 1024
#define C_N 1024
#define BM 128
#define BN 128
#define BK 128

typedef __attribute__((ext_vector_type(8))) __bf16 bf16x8;
typedef __attribute__((ext_vector_type(16))) float floatx16;

__device__ inline unsigned short f2bf(float f) {
  union { float f; unsigned int u; } cv; cv.f = f;
  unsigned int b = cv.u;
  unsigned int r = (b + 0x7FFFu + ((b >> 16) & 1u)) >> 16;  // RNE
  return (unsigned short)r;
}
__device__ inline float d4(const float4 a) {
  return a.x * a.x + a.y * a.y + a.z * a.z + a.w * a.w;
}
__device__ inline ushort4 pk4(const float4 v, const float s) {
  ushort4 u;
  u.x = f2bf(v.x * s); u.y = f2bf(v.y * s);
  u.z = f2bf(v.z * s); u.w = f2bf(v.w * s);
  return u;
}

// ---------------------------------------------------------------------------
// prep_kernel: unchanged from R7 (1024 fat blocks).
// ---------------------------------------------------------------------------
__global__ __launch_bounds__(256) void prep_kernel(
    const float* __restrict__ emb_i, const float* __restrict__ emb_j,
    const int* __restrict__ labels,
    unsigned short* __restrict__ z_j, unsigned short* __restrict__ proto,
    float* __restrict__ p2, float* __restrict__ out) {
  __shared__ float sx[4][8];
  __shared__ int list[8];
  __shared__ int scnt;

  const int t = threadIdx.x;
  const int lane = t & 63;
  const int wid = t >> 6;
  const int blk = blockIdx.x;

  if (t == 0) scnt = 0;
  if (blk == 0 && t == 0) out[0] = 0.0f;

#pragma unroll
  for (int it = 0; it < 2; ++it) {
    const int row = blk * 8 + it * 4 + wid;
    const float4* src = (const float4*)(emb_j + (size_t)row * D_N);
    const float4 v0 = src[lane], v1 = src[lane + 64];
    const float4 v2 = src[lane + 128], v3 = src[lane + 192];
    float ss = d4(v0) + d4(v1) + d4(v2) + d4(v3);
    for (int o = 32; o; o >>= 1) ss += __shfl_xor(ss, o, 64);
    const float inv = 1.0f / fmaxf(sqrtf(ss), 1e-12f);
    ushort4* dst = (ushort4*)(z_j + (size_t)row * D_N);
    dst[lane] = pk4(v0, inv);
    dst[lane + 64] = pk4(v1, inv);
    dst[lane + 128] = pk4(v2, inv);
    dst[lane + 192] = pk4(v3, inv);
  }

  const int c = blk;
  __syncthreads();
  const int4* lab4 = (const int4*)labels;
  for (int i = 0; i < 8; ++i) {
    const int q = i * 256 + t;
    const int4 L = lab4[q];
    const int base = q * 4;
    if (L.x == c) list[atomicAdd(&scnt, 1) & 7] = base;
    if (L.y == c) list[atomicAdd(&scnt, 1) & 7] = base + 1;
    if (L.z == c) list[atomicAdd(&scnt, 1) & 7] = base + 2;
    if (L.w == c) list[atomicAdd(&scnt, 1) & 7] = base + 3;
  }
  __syncthreads();

  const float* base = emb_i + wid * 256;
  float4 v[8];
  float ss[8];
#pragma unroll
  for (int k = 0; k < 8; ++k) {
    v[k] = ((const float4*)(base + (size_t)list[k] * D_N))[lane];
    ss[k] = d4(v[k]);
  }
#pragma unroll
  for (int k = 0; k < 8; ++k)
    for (int o = 32; o; o >>= 1) ss[k] += __shfl_xor(ss[k], o, 64);
  if (lane == 0) {
#pragma unroll
    for (int k = 0; k < 8; ++k) sx[wid][k] = ss[k];
  }
  __syncthreads();

  float4 a = make_float4(0.f, 0.f, 0.f, 0.f);
#pragma unroll
  for (int k = 0; k < 8; ++k) {
    const float tot = sx[0][k] + sx[1][k] + sx[2][k] + sx[3][k];
    const float iv = 1.0f / fmaxf(sqrtf(tot), 1e-12f);
    a.x += v[k].x * iv; a.y += v[k].y * iv;
    a.z += v[k].z * iv; a.w += v[k].w * iv;
  }
  a.x *= 0.125f; a.y *= 0.125f; a.z *= 0.125f; a.w *= 0.125f;

  float pp = d4(a);
  for (int o = 32; o; o >>= 1) pp += __shfl_xor(pp, o, 64);
  __syncthreads();
  if (lane == 0) sx[wid][0] = pp;
  __syncthreads();
  if (t == 0) p2[c] = sx[0][0] + sx[1][0] + sx[2][0] + sx[3][0];

  ((ushort4*)(proto + (size_t)c * D_N + wid * 256))[lane] = pk4(a, 1.0f);
}

// ---------------------------------------------------------------------------
// gemm_loss_kernel v3: 32x32x16 bf16 MFMA (half the MFMA instrs of 16x16x32),
// BK=128 (half the barriers), 128x128 tile, global_load_lds width=16,
// XOR-swizzled LDS (16-byte chunks; chunk slot = logical ^ (row&7)),
// 2x2 waves of 64x64, each wave 2x2 blocks of 32x32. Fused BCE epilogue.
// C/D layout (m74/m101-verified): col=lane&31, row=(reg&3)+8*(reg>>2)+4*(lane>>5).
// ---------------------------------------------------------------------------
__global__ __launch_bounds__(256) void gemm_loss_kernel(
    const unsigned short* __restrict__ Zj,   // [B,D] bf16
    const unsigned short* __restrict__ P,    // [C,D] bf16
    const float* __restrict__ p2,            // [C]
    const int* __restrict__ labels,          // [B]
    float* __restrict__ out) {               // scalar (zeroed by prep)
  __shared__ __align__(16) unsigned short As[BM * BK];  // 32 KB
  __shared__ __align__(16) unsigned short Bs[BN * BK];  // 32 KB
  __shared__ float sred[4];

  const int t = threadIdx.x;
  const int lane = t & 63;
  const int wid = t >> 6;
  const int wm = (wid >> 1) * 64;
  const int wn = (wid & 1) * 64;
  const int bm = blockIdx.x;
  const int bn = blockIdx.y;

  floatx16 acc[2][2];
#pragma unroll
  for (int i = 0; i < 2; ++i)
#pragma unroll
    for (int j = 0; j < 2; ++j)
      for (int r = 0; r < 16; ++r) acc[i][j][r] = 0.f;

  // staging: 8 passes; pass p: thread t -> row p*16 + (t>>4), chunk slot t&15,
  // fetching global chunk (t&15)^(row&7). LDS dest = base + t*16B.
  const int srow = t >> 4;
  const int g = (t & 15) ^ (srow & 7);
  const unsigned short* Ag = Zj + (size_t)(bm * BM + srow) * D_N + g * 8;
  const unsigned short* Bg = P + (size_t)(bn * BN + srow) * D_N + g * 8;
  unsigned short* Al = As + t * 8;
  unsigned short* Bl = Bs + t * 8;

  // ds_read row bases (ushort units); row&7 == lane&7 for all frag rows.
  const int ar0 = (wm + (lane & 31)) * BK;
  const int ar1 = (wm + 32 + (lane & 31)) * BK;
  const int br0 = (wn + (lane & 31)) * BK;
  const int br1 = (wn + 32 + (lane & 31)) * BK;
  const int h = lane >> 5;       // K-half selector
  const int q = lane & 7;        // row&7 for swizzle inverse

  for (int k0 = 0; k0 < D_N; k0 += BK) {
#pragma unroll
    for (int it = 0; it < 8; ++it) {
      __builtin_amdgcn_global_load_lds(
          (const __attribute__((address_space(1))) void*)(Ag + (size_t)it * 16 * D_N + k0),
          (__attribute__((address_space(3))) void*)(Al + it * 2048), 16, 0, 0);
      __builtin_amdgcn_global_load_lds(
          (const __attribute__((address_space(1))) void*)(Bg + (size_t)it * 16 * D_N + k0),
          (__attribute__((address_space(3))) void*)(Bl + it * 2048), 16, 0, 0);
    }
    __syncthreads();
#pragma unroll
    for (int kk8 = 0; kk8 < 8; ++kk8) {
      const int swz = (((kk8 * 2 + h) ^ q)) << 3;  // chunk*8 ushorts
      bf16x8 a0 = *(const bf16x8*)(As + ar0 + swz);
      bf16x8 a1 = *(const bf16x8*)(As + ar1 + swz);
      bf16x8 b0 = *(const bf16x8*)(Bs + br0 + swz);
      bf16x8 b1 = *(const bf16x8*)(Bs + br1 + swz);
      acc[0][0] = __builtin_amdgcn_mfma_f32_32x32x16_bf16(a0, b0, acc[0][0], 0, 0, 0);
      acc[0][1] = __builtin_amdgcn_mfma_f32_32x32x16_bf16(a0, b1, acc[0][1], 0, 0, 0);
      acc[1][0] = __builtin_amdgcn_mfma_f32_32x32x16_bf16(a1, b0, acc[1][0], 0, 0, 0);
      acc[1][1] = __builtin_amdgcn_mfma_f32_32x32x16_bf16(a1, b1, acc[1][1], 0, 0, 0);
    }
    __syncthreads();
  }

  // epilogue: 32x32 C/D layout col=lane&31, row=(reg&3)+8*(reg>>2)+4*(lane>>5)
  const int colbase = bn * BN + wn + (lane & 31);
  float lsum = 0.f;
#pragma unroll
  for (int mb = 0; mb < 2; ++mb) {
    const int rowbase = bm * BM + wm + mb * 32 + 4 * h;
    int labv[16];
#pragma unroll
    for (int reg = 0; reg < 16; ++reg)
      labv[reg] = labels[rowbase + (reg & 3) + 8 * (reg >> 2)];
#pragma unroll
    for (int nb = 0; nb < 2; ++nb) {
      const int col = colbase + nb * 32;
      const float p2c = p2[col];
#pragma unroll
      for (int reg = 0; reg < 16; ++reg) {
        const float dot = acc[mb][nb][reg];
        const float d2 = 1.0f + p2c - 2.0f * dot;
        const float s = 2.0f - sqrtf(fmaxf(d2, 0.0f));
        const float sp = fmaxf(s, 0.0f) + log1pf(expf(-fabsf(s)));
        lsum += sp - ((labv[reg] == col) ? s : 0.0f);
      }
    }
  }
  for (int o = 32; o; o >>= 1) lsum += __shfl_xor(lsum, o, 64);
  if (lane == 0) sred[wid] = lsum;
  __syncthreads();
  if (t == 0)
    atomicAdd(out, (sred[0] + sred[1] + sred[2] + sred[3]) *
                       (1.0f / ((float)B_N * (float)C_N)));
}

// ---------------------------------------------------------------------------
extern "C" void kernel_launch(void* const* d_in, const int* in_sizes, int n_in,
                              void* d_out, int out_size, void* d_ws, size_t ws_size,
                              hipStream_t stream) {
  const float* emb_i = (const float*)d_in[0];
  const float* emb_j = (const float*)d_in[1];
  const int* labels = (const int*)d_in[2];
  float* out = (float*)d_out;

  char* ws = (char*)d_ws;
  unsigned short* z_j = (unsigned short*)ws;                         // 16 MB
  unsigned short* proto = (unsigned short*)(ws + (size_t)16777216);  // 2 MB
  float* p2 = (float*)(ws + (size_t)18874368);                       // 4 KB

  prep_kernel<<<dim3(C_N), 256, 0, stream>>>(emb_i, emb_j, labels, z_j,
                                             proto, p2, out);
  gemm_loss_kernel<<<dim3(B_N / BM, C_N / BN), 256, 0, stream>>>(z_j, proto,
                                                                 p2, labels, out);
}